// Round 1
// baseline (4596.201 us; speedup 1.0000x reference)
//
#include <hip/hip_runtime.h>
#include <hip/hip_bf16.h>

#define T_STEPS 2048
#define HDIM 256
#define VOUT 32000

// ---------- int8 dot4 (signed) with fallback ----------
#if defined(__has_builtin)
#if __has_builtin(__builtin_amdgcn_sdot4)
#define HAVE_SDOT4 1
#endif
#endif

__device__ __forceinline__ int dot4i8(int a, int b, int c) {
#ifdef HAVE_SDOT4
    return __builtin_amdgcn_sdot4(a, b, c, false);
#else
#pragma unroll
    for (int k = 0; k < 4; ++k) {
        int av = (a << (24 - 8 * k)) >> 24;
        int bv = (b << (24 - 8 * k)) >> 24;
        c += av * bv;
    }
    return c;
#endif
}

__device__ __forceinline__ float fast_sigmoid(float x) {
    return 1.0f / (1.0f + __expf(-x));
}
__device__ __forceinline__ float fast_tanh(float x) {
    float ax = fabsf(x);
    float e = __expf(-2.0f * ax);
    float t = 1.0f - 2.0f * e / (1.0f + e);
    return copysignf(t, x);
}

// ---------- quantize a 768x256 fp32 matrix to int8 (per-row scale) ----------
// grid 768 blocks x 64 threads (one wave per row)
__global__ void k_quant(const float* __restrict__ W, int* __restrict__ wq,
                        float* __restrict__ sc) {
    int row = blockIdx.x;
    int t = threadIdx.x;
    float4 w = ((const float4*)(W + (size_t)row * HDIM))[t];
    float m = fmaxf(fmaxf(fabsf(w.x), fabsf(w.y)), fmaxf(fabsf(w.z), fabsf(w.w)));
#pragma unroll
    for (int off = 32; off; off >>= 1) m = fmaxf(m, __shfl_xor(m, off));
    float inv = (m > 0.0f) ? 127.0f / m : 0.0f;
    float scale = (m > 0.0f) ? m * (1.0f / 127.0f) : 0.0f;
    int q0 = __float2int_rn(w.x * inv); q0 = max(-127, min(127, q0));
    int q1 = __float2int_rn(w.y * inv); q1 = max(-127, min(127, q1));
    int q2 = __float2int_rn(w.z * inv); q2 = max(-127, min(127, q2));
    int q3 = __float2int_rn(w.w * inv); q3 = max(-127, min(127, q3));
    int packed = (q0 & 255) | ((q1 & 255) << 8) | ((q2 & 255) << 16) | ((q3 & 255) << 24);
    wq[row * 64 + t] = packed;
    if (t == 0) sc[row] = scale;
}

// ---------- Phase A: gi[t][row] = W_ih @ x_t + b_ih  (x_t = emb[tok] (opt relu)) ----------
// grid T_STEPS blocks x 256 threads
__global__ __launch_bounds__(256) void k_gi(const int* __restrict__ toks,
                                            const float* __restrict__ emb,
                                            const float* __restrict__ W,
                                            const float* __restrict__ b,
                                            float* __restrict__ gi, int do_relu) {
    __shared__ float4 xs[64];
    int t = blockIdx.x;
    int tid = threadIdx.x;
    int tok = toks[t];
    if (tid < 64) {
        float4 x = ((const float4*)(emb + (size_t)tok * HDIM))[tid];
        if (do_relu) {
            x.x = fmaxf(x.x, 0.0f); x.y = fmaxf(x.y, 0.0f);
            x.z = fmaxf(x.z, 0.0f); x.w = fmaxf(x.w, 0.0f);
        }
        xs[tid] = x;
    }
    __syncthreads();
#pragma unroll
    for (int g = 0; g < 3; ++g) {
        int row = tid + g * 256;
        const float4* wr = (const float4*)(W + (size_t)row * HDIM);
        float acc = b[row];
#pragma unroll 16
        for (int k = 0; k < 64; ++k) {
            float4 w = wr[k];
            float4 x = xs[k];
            acc += w.x * x.x + w.y * x.y + w.z * x.z + w.w * x.w;
        }
        gi[(size_t)t * 768 + row] = acc;
    }
}

// ---------- Phase B: the sequential double-GRU. ONE workgroup, weights in VGPRs ----------
// 768 threads = 12 waves = 3 waves/SIMD on one CU. Each thread owns one output row
// of both W_hh matrices as 64 packed-int8 dwords each (128 VGPRs of weights).
__global__ __launch_bounds__(768, 3) void k_gru(
    const int* __restrict__ wq_e, const float* __restrict__ sc_e,
    const float* __restrict__ bhh_e, const float* __restrict__ gi_e,
    const int* __restrict__ wq_d, const float* __restrict__ sc_d,
    const float* __restrict__ bhh_d, const float* __restrict__ gi_d,
    float* __restrict__ h_all) {
    __shared__ float Y[768];
    __shared__ float GN[256];
    __shared__ __align__(16) int HQ[64];  // 256 int8-quantized h values

    const int tid = threadIdx.x;
    const int row = tid;

    int we[64], wd[64];
    {
        const int4* pe = (const int4*)(wq_e + row * 64);
        const int4* pd = (const int4*)(wq_d + row * 64);
#pragma unroll
        for (int i = 0; i < 16; ++i) {
            int4 a = pe[i];
            int4 bq = pd[i];
            we[4 * i + 0] = a.x;  we[4 * i + 1] = a.y;
            we[4 * i + 2] = a.z;  we[4 * i + 3] = a.w;
            wd[4 * i + 0] = bq.x; wd[4 * i + 1] = bq.y;
            wd[4 * i + 2] = bq.z; wd[4 * i + 3] = bq.w;
        }
    }
    const float se = sc_e[row] * (1.0f / 127.0f);  // weight scale * h scale
    const float sd = sc_d[row] * (1.0f / 127.0f);
    const float be = bhh_e[row];
    const float bd = bhh_d[row];
    const bool lead = (tid < 256);
    float h = 0.0f;  // gate threads keep h[tid] in-register across all steps
    if (tid < 64) HQ[tid] = 0;  // h0 = 0
    __syncthreads();

    const float* ge = gi_e + row;
    const float* gd = gi_d + row;
    float* hop = h_all + tid;

    for (int t = 0; t < T_STEPS; ++t) {
        float gie = *ge; ge += 768;  // issued early, hidden under dot
        float gid = *gd; gd += 768;

        // ---- encoder half: gh = W_hh_enc @ h ----
        {
            int acc = 0;
            const int4* hq4 = (const int4*)HQ;
#pragma unroll
            for (int c = 0; c < 16; ++c) {
                int4 hv = hq4[c];  // broadcast LDS read
                acc = dot4i8(we[4 * c + 0], hv.x, acc);
                acc = dot4i8(we[4 * c + 1], hv.y, acc);
                acc = dot4i8(we[4 * c + 2], hv.z, acc);
                acc = dot4i8(we[4 * c + 3], hv.w, acc);
            }
            float y = se * (float)acc + be;
            if (row < 512) Y[row] = y + gie;          // r,z rows: fold gi in
            else { Y[row] = y; GN[row - 512] = gie; } // n rows: keep gi separate
        }
        __syncthreads();
        if (lead) {
            float r = fast_sigmoid(Y[tid]);
            float z = fast_sigmoid(Y[256 + tid]);
            float n = fast_tanh(GN[tid] + r * Y[512 + tid]);
            h = (1.0f - z) * n + z * h;
            ((signed char*)HQ)[tid] = (signed char)__float2int_rn(h * 127.0f);
        }
        __syncthreads();

        // ---- decoder half: gh = W_hh_dec @ h ----
        {
            int acc = 0;
            const int4* hq4 = (const int4*)HQ;
#pragma unroll
            for (int c = 0; c < 16; ++c) {
                int4 hv = hq4[c];
                acc = dot4i8(wd[4 * c + 0], hv.x, acc);
                acc = dot4i8(wd[4 * c + 1], hv.y, acc);
                acc = dot4i8(wd[4 * c + 2], hv.z, acc);
                acc = dot4i8(wd[4 * c + 3], hv.w, acc);
            }
            float y = sd * (float)acc + bd;
            if (row < 512) Y[row] = y + gid;
            else { Y[row] = y; GN[row - 512] = gid; }
        }
        __syncthreads();
        if (lead) {
            float r = fast_sigmoid(Y[tid]);
            float z = fast_sigmoid(Y[256 + tid]);
            float n = fast_tanh(GN[tid] + r * Y[512 + tid]);
            h = (1.0f - z) * n + z * h;
            *hop = h; hop += 256;  // save fp32 h for Phase C
            ((signed char*)HQ)[tid] = (signed char)__float2int_rn(h * 127.0f);
        }
        __syncthreads();
    }
}

// ---------- Phase C1: logits = H_all(2048x256) @ out_W^T(256x32000) + out_b ----------
// 64x64 tiles, 256 threads as 16x16, 4x4 microtile, K chunked by 64.
__global__ __launch_bounds__(256) void k_logits(const float* __restrict__ h_all,
                                                const float* __restrict__ out_W,
                                                const float* __restrict__ out_b,
                                                float* __restrict__ out) {
    __shared__ float As[64][68];  // As[k][t]
    __shared__ float Bs[64][68];  // Bs[k][v]
    const int vb = blockIdx.x * 64;
    const int tb = blockIdx.y * 64;
    const int tid = threadIdx.x;
    const int tx = tid & 15;
    const int ty = tid >> 4;
    const int tl = tid & 63;
    const int kg = tid >> 6;

    float acc[4][4];
#pragma unroll
    for (int i = 0; i < 4; ++i)
#pragma unroll
        for (int j = 0; j < 4; ++j) acc[i][j] = 0.0f;

    for (int k0 = 0; k0 < HDIM; k0 += 64) {
#pragma unroll
        for (int j = 0; j < 4; ++j) {
            float4 a = *(const float4*)&h_all[(size_t)(tb + tl) * HDIM + k0 + kg * 16 + 4 * j];
            int kk = kg * 16 + 4 * j;
            As[kk + 0][tl] = a.x; As[kk + 1][tl] = a.y;
            As[kk + 2][tl] = a.z; As[kk + 3][tl] = a.w;
            float4 b = *(const float4*)&out_W[(size_t)(vb + tl) * HDIM + k0 + kg * 16 + 4 * j];
            Bs[kk + 0][tl] = b.x; Bs[kk + 1][tl] = b.y;
            Bs[kk + 2][tl] = b.z; Bs[kk + 3][tl] = b.w;
        }
        __syncthreads();
#pragma unroll 16
        for (int k = 0; k < 64; ++k) {
            float4 a = *(const float4*)&As[k][ty * 4];
            float4 b = *(const float4*)&Bs[k][tx * 4];
            acc[0][0] += a.x * b.x; acc[0][1] += a.x * b.y; acc[0][2] += a.x * b.z; acc[0][3] += a.x * b.w;
            acc[1][0] += a.y * b.x; acc[1][1] += a.y * b.y; acc[1][2] += a.y * b.z; acc[1][3] += a.y * b.w;
            acc[2][0] += a.z * b.x; acc[2][1] += a.z * b.y; acc[2][2] += a.z * b.z; acc[2][3] += a.z * b.w;
            acc[3][0] += a.w * b.x; acc[3][1] += a.w * b.y; acc[3][2] += a.w * b.z; acc[3][3] += a.w * b.w;
        }
        __syncthreads();
    }
    float4 bias = *(const float4*)&out_b[vb + tx * 4];
#pragma unroll
    for (int i = 0; i < 4; ++i) {
        float4 o;
        o.x = acc[i][0] + bias.x; o.y = acc[i][1] + bias.y;
        o.z = acc[i][2] + bias.z; o.w = acc[i][3] + bias.w;
        *(float4*)&out[(size_t)(tb + ty * 4 + i) * VOUT + vb + tx * 4] = o;
    }
}

// ---------- Phase C2: per-row logsumexp (online) ----------
__global__ __launch_bounds__(256) void k_lse(const float* __restrict__ out,
                                             float* __restrict__ lse) {
    const int t = blockIdx.x;
    const int tid = threadIdx.x;
    const float* rowp = out + (size_t)t * VOUT;
    float m = -3.0e38f, l = 0.0f;
    for (int v = tid; v < VOUT; v += 256) {
        float x = rowp[v];
        float M = fmaxf(m, x);
        l = l * __expf(m - M) + __expf(x - M);
        m = M;
    }
#pragma unroll
    for (int off = 32; off; off >>= 1) {
        float m2 = __shfl_xor(m, off);
        float l2 = __shfl_xor(l, off);
        float M = fmaxf(m, m2);
        l = l * __expf(m - M) + l2 * __expf(m2 - M);
        m = M;
    }
    __shared__ float sm[4], sl[4];
    int lane = tid & 63, w = tid >> 6;
    if (lane == 0) { sm[w] = m; sl[w] = l; }
    __syncthreads();
    if (tid == 0) {
        float M = fmaxf(fmaxf(sm[0], sm[1]), fmaxf(sm[2], sm[3]));
        float L = sl[0] * __expf(sm[0] - M) + sl[1] * __expf(sm[1] - M) +
                  sl[2] * __expf(sm[2] - M) + sl[3] * __expf(sm[3] - M);
        lse[t] = M + __logf(L);
    }
}

// ---------- Phase C3: out -= lse[t] ----------
__global__ __launch_bounds__(256) void k_sub(float* __restrict__ out,
                                             const float* __restrict__ lse) {
    const int t = blockIdx.y;
    const int v4 = blockIdx.x * 256 + threadIdx.x;
    if (v4 < VOUT / 4) {
        float s = lse[t];
        float4* p = (float4*)(out + (size_t)t * VOUT) + v4;
        float4 o = *p;
        o.x -= s; o.y -= s; o.z -= s; o.w -= s;
        *p = o;
    }
}

extern "C" void kernel_launch(void* const* d_in, const int* in_sizes, int n_in,
                              void* d_out, int out_size, void* d_ws, size_t ws_size,
                              hipStream_t stream) {
    (void)in_sizes; (void)n_in; (void)out_size; (void)ws_size;
    const int*   src      = (const int*)d_in[0];
    const int*   trg      = (const int*)d_in[1];
    const float* enc_emb  = (const float*)d_in[2];
    const float* enc_W_ih = (const float*)d_in[3];
    const float* enc_W_hh = (const float*)d_in[4];
    const float* enc_b_ih = (const float*)d_in[5];
    const float* enc_b_hh = (const float*)d_in[6];
    const float* dec_emb  = (const float*)d_in[7];
    const float* dec_W_ih = (const float*)d_in[8];
    const float* dec_W_hh = (const float*)d_in[9];
    const float* dec_b_ih = (const float*)d_in[10];
    const float* dec_b_hh = (const float*)d_in[11];
    const float* out_W    = (const float*)d_in[12];
    const float* out_b    = (const float*)d_in[13];
    float* out = (float*)d_out;

    char* ws = (char*)d_ws;
    float* gi_e  = (float*)ws; ws += (size_t)T_STEPS * 768 * 4;
    float* gi_d  = (float*)ws; ws += (size_t)T_STEPS * 768 * 4;
    float* h_all = (float*)ws; ws += (size_t)T_STEPS * HDIM * 4;
    float* lse   = (float*)ws; ws += (size_t)T_STEPS * 4;
    float* sc_e  = (float*)ws; ws += 768 * 4;
    float* sc_d  = (float*)ws; ws += 768 * 4;
    int*   wq_e  = (int*)ws;   ws += 768 * 64 * 4;
    int*   wq_d  = (int*)ws;   ws += 768 * 64 * 4;

    k_quant<<<768, 64, 0, stream>>>(enc_W_hh, wq_e, sc_e);
    k_quant<<<768, 64, 0, stream>>>(dec_W_hh, wq_d, sc_d);
    k_gi<<<T_STEPS, 256, 0, stream>>>(src, enc_emb, enc_W_ih, enc_b_ih, gi_e, 0);
    k_gi<<<T_STEPS, 256, 0, stream>>>(trg, dec_emb, dec_W_ih, dec_b_ih, gi_d, 1);
    k_gru<<<1, 768, 0, stream>>>(wq_e, sc_e, enc_b_hh, gi_e,
                                 wq_d, sc_d, dec_b_hh, gi_d, h_all);
    k_logits<<<dim3(VOUT / 64, T_STEPS / 64), 256, 0, stream>>>(h_all, out_W, out_b, out);
    k_lse<<<T_STEPS, 256, 0, stream>>>(out, lse);
    k_sub<<<dim3(32, T_STEPS), 256, 0, stream>>>(out, lse);
}

// Round 2
// 4463.458 us; speedup vs baseline: 1.0297x; 1.0297x over previous
//
#include <hip/hip_runtime.h>
#include <hip/hip_bf16.h>

#define T_STEPS 2048
#define HDIM 256
#define VOUT 32000

typedef short short8 __attribute__((ext_vector_type(8)));
typedef float f32x4 __attribute__((ext_vector_type(4)));

// ---------- int8 dot4 (signed) with fallback ----------
#if defined(__has_builtin)
#if __has_builtin(__builtin_amdgcn_sdot4)
#define HAVE_SDOT4 1
#endif
#endif

__device__ __forceinline__ int dot4i8(int a, int b, int c) {
#ifdef HAVE_SDOT4
    return __builtin_amdgcn_sdot4(a, b, c, false);
#else
#pragma unroll
    for (int k = 0; k < 4; ++k) {
        int av = (a << (24 - 8 * k)) >> 24;
        int bv = (b << (24 - 8 * k)) >> 24;
        c += av * bv;
    }
    return c;
#endif
}

__device__ __forceinline__ float fast_sigmoid(float x) {
    return 1.0f / (1.0f + __expf(-x));
}
__device__ __forceinline__ float fast_tanh(float x) {
    float ax = fabsf(x);
    float e = __expf(-2.0f * ax);
    float t = 1.0f - 2.0f * e / (1.0f + e);
    return copysignf(t, x);
}

// ---------- quantize a 768x256 fp32 matrix to int8 (per-row scale) ----------
__global__ void k_quant(const float* __restrict__ W, int* __restrict__ wq,
                        float* __restrict__ sc) {
    int row = blockIdx.x;
    int t = threadIdx.x;
    float4 w = ((const float4*)(W + (size_t)row * HDIM))[t];
    float m = fmaxf(fmaxf(fabsf(w.x), fabsf(w.y)), fmaxf(fabsf(w.z), fabsf(w.w)));
#pragma unroll
    for (int off = 32; off; off >>= 1) m = fmaxf(m, __shfl_xor(m, off));
    float inv = (m > 0.0f) ? 127.0f / m : 0.0f;
    float scale = (m > 0.0f) ? m * (1.0f / 127.0f) : 0.0f;
    int q0 = __float2int_rn(w.x * inv); q0 = max(-127, min(127, q0));
    int q1 = __float2int_rn(w.y * inv); q1 = max(-127, min(127, q1));
    int q2 = __float2int_rn(w.z * inv); q2 = max(-127, min(127, q2));
    int q3 = __float2int_rn(w.w * inv); q3 = max(-127, min(127, q3));
    int packed = (q0 & 255) | ((q1 & 255) << 8) | ((q2 & 255) << 16) | ((q3 & 255) << 24);
    wq[row * 64 + t] = packed;
    if (t == 0) sc[row] = scale;
}

// ---------- fp32 -> bf16 (RNE, manual to keep ushort storage) ----------
__global__ __launch_bounds__(256) void k_cvt(const float* __restrict__ in,
                                             unsigned short* __restrict__ out, int n4) {
    int i = blockIdx.x * 256 + threadIdx.x;
    if (i < n4) {
        float4 v = ((const float4*)in)[i];
        unsigned int u[4] = {__float_as_uint(v.x), __float_as_uint(v.y),
                             __float_as_uint(v.z), __float_as_uint(v.w)};
        ushort4 o;
        o.x = (unsigned short)((u[0] + 0x7FFFu + ((u[0] >> 16) & 1)) >> 16);
        o.y = (unsigned short)((u[1] + 0x7FFFu + ((u[1] >> 16) & 1)) >> 16);
        o.z = (unsigned short)((u[2] + 0x7FFFu + ((u[2] >> 16) & 1)) >> 16);
        o.w = (unsigned short)((u[3] + 0x7FFFu + ((u[3] >> 16) & 1)) >> 16);
        ((ushort4*)out)[i] = o;
    }
}

// ---------- Phase A: gi[t][row] = W_ih @ x_t + b_ih ----------
__global__ __launch_bounds__(256) void k_gi(const int* __restrict__ toks,
                                            const float* __restrict__ emb,
                                            const float* __restrict__ W,
                                            const float* __restrict__ b,
                                            float* __restrict__ gi, int do_relu) {
    __shared__ float4 xs[64];
    int t = blockIdx.x;
    int tid = threadIdx.x;
    int tok = toks[t];
    if (tid < 64) {
        float4 x = ((const float4*)(emb + (size_t)tok * HDIM))[tid];
        if (do_relu) {
            x.x = fmaxf(x.x, 0.0f); x.y = fmaxf(x.y, 0.0f);
            x.z = fmaxf(x.z, 0.0f); x.w = fmaxf(x.w, 0.0f);
        }
        xs[tid] = x;
    }
    __syncthreads();
#pragma unroll
    for (int g = 0; g < 3; ++g) {
        int row = tid + g * 256;
        const float4* wr = (const float4*)(W + (size_t)row * HDIM);
        float acc = b[row];
#pragma unroll 16
        for (int k = 0; k < 64; ++k) {
            float4 w = wr[k];
            float4 x = xs[k];
            acc += w.x * x.x + w.y * x.y + w.z * x.z + w.w * x.w;
        }
        gi[(size_t)t * 768 + row] = acc;
    }
}

// ---------- Phase B: sequential double-GRU, one workgroup, 4-way K-split ----------
// Lane l of wave w: chunk c=l&3 (64 h values = 16 dwords), group g=l>>2.
// Computes partials for rows w*64+g*4+{0..3} over its chunk; reduce-scatter over
// the 4 chunk lanes leaves row w*64+g*4+c == tid in this lane -> epilogue local.
__global__ __launch_bounds__(768, 3) void k_gru(
    const int* __restrict__ wq_e, const float* __restrict__ sc_e,
    const float* __restrict__ bhh_e, const float* __restrict__ gi_e,
    const int* __restrict__ wq_d, const float* __restrict__ sc_d,
    const float* __restrict__ bhh_d, const float* __restrict__ gi_d,
    float* __restrict__ h_all) {
    __shared__ float Y[768];
    __shared__ float GN[256];
    __shared__ __align__(16) int HQ[64];  // 256 int8-quantized h values

    const int tid = threadIdx.x;
    const int w = tid >> 6;
    const int l = tid & 63;
    const int c = l & 3;
    const int g = l >> 2;

    // weights: 4 partial rows x 16 dwords per matrix
    int we[4][16], wd[4][16];
#pragma unroll
    for (int j = 0; j < 4; ++j) {
        const int4* pe = (const int4*)(wq_e + ((w * 64 + g * 4 + j) * 64 + c * 16));
        const int4* pd = (const int4*)(wq_d + ((w * 64 + g * 4 + j) * 64 + c * 16));
#pragma unroll
        for (int i = 0; i < 4; ++i) {
            int4 a = pe[i];
            we[j][4 * i + 0] = a.x; we[j][4 * i + 1] = a.y;
            we[j][4 * i + 2] = a.z; we[j][4 * i + 3] = a.w;
            int4 bq = pd[i];
            wd[j][4 * i + 0] = bq.x; wd[j][4 * i + 1] = bq.y;
            wd[j][4 * i + 2] = bq.z; wd[j][4 * i + 3] = bq.w;
        }
    }
    const float se = sc_e[tid] * (1.0f / 127.0f);
    const float sd = sc_d[tid] * (1.0f / 127.0f);
    const float be = bhh_e[tid];
    const float bd = bhh_d[tid];
    const bool lead = (tid < 256);
    const int c0 = c & 1;
    const int c1 = c & 2;
    float h = 0.0f;
    if (tid < 64) HQ[tid] = 0;
    __syncthreads();

    const float* ge = gi_e + tid;
    const float* gd = gi_d + tid;
    float* hop = h_all + tid;
    const int4* hq4 = (const int4*)HQ;

    for (int t = 0; t < T_STEPS; ++t) {
        float gie = *ge; ge += 768;
        float gid = *gd; gd += 768;

        // ---- encoder half ----
        {
            int4 h0 = hq4[c * 4 + 0];
            int4 h1 = hq4[c * 4 + 1];
            int4 h2 = hq4[c * 4 + 2];
            int4 h3 = hq4[c * 4 + 3];
            int p[4];
#pragma unroll
            for (int j = 0; j < 4; ++j) {
                int a = 0;
                a = dot4i8(we[j][0], h0.x, a);  a = dot4i8(we[j][1], h0.y, a);
                a = dot4i8(we[j][2], h0.z, a);  a = dot4i8(we[j][3], h0.w, a);
                a = dot4i8(we[j][4], h1.x, a);  a = dot4i8(we[j][5], h1.y, a);
                a = dot4i8(we[j][6], h1.z, a);  a = dot4i8(we[j][7], h1.w, a);
                a = dot4i8(we[j][8], h2.x, a);  a = dot4i8(we[j][9], h2.y, a);
                a = dot4i8(we[j][10], h2.z, a); a = dot4i8(we[j][11], h2.w, a);
                a = dot4i8(we[j][12], h3.x, a); a = dot4i8(we[j][13], h3.y, a);
                a = dot4i8(we[j][14], h3.z, a); a = dot4i8(we[j][15], h3.w, a);
                p[j] = a;
            }
            // reduce-scatter over chunk lanes; lane ends with row == tid
            int s0 = c0 ? p[0] : p[1];
            int s1 = c0 ? p[2] : p[3];
            int r0 = (c0 ? p[1] : p[0]) + __shfl_xor(s0, 1);
            int r1 = (c0 ? p[3] : p[2]) + __shfl_xor(s1, 1);
            int s2 = c1 ? r0 : r1;
            int fin = (c1 ? r1 : r0) + __shfl_xor(s2, 2);
            float y = se * (float)fin + be;
            if (tid < 512) Y[tid] = y + gie;
            else { Y[tid] = y; GN[tid - 512] = gie; }
        }
        __syncthreads();
        if (lead) {
            float r = fast_sigmoid(Y[tid]);
            float z = fast_sigmoid(Y[256 + tid]);
            float n = fast_tanh(GN[tid] + r * Y[512 + tid]);
            h = (1.0f - z) * n + z * h;
            ((signed char*)HQ)[tid] = (signed char)__float2int_rn(h * 127.0f);
        }
        __syncthreads();

        // ---- decoder half ----
        {
            int4 h0 = hq4[c * 4 + 0];
            int4 h1 = hq4[c * 4 + 1];
            int4 h2 = hq4[c * 4 + 2];
            int4 h3 = hq4[c * 4 + 3];
            int p[4];
#pragma unroll
            for (int j = 0; j < 4; ++j) {
                int a = 0;
                a = dot4i8(wd[j][0], h0.x, a);  a = dot4i8(wd[j][1], h0.y, a);
                a = dot4i8(wd[j][2], h0.z, a);  a = dot4i8(wd[j][3], h0.w, a);
                a = dot4i8(wd[j][4], h1.x, a);  a = dot4i8(wd[j][5], h1.y, a);
                a = dot4i8(wd[j][6], h1.z, a);  a = dot4i8(wd[j][7], h1.w, a);
                a = dot4i8(wd[j][8], h2.x, a);  a = dot4i8(wd[j][9], h2.y, a);
                a = dot4i8(wd[j][10], h2.z, a); a = dot4i8(wd[j][11], h2.w, a);
                a = dot4i8(wd[j][12], h3.x, a); a = dot4i8(wd[j][13], h3.y, a);
                a = dot4i8(wd[j][14], h3.z, a); a = dot4i8(wd[j][15], h3.w, a);
                p[j] = a;
            }
            int s0 = c0 ? p[0] : p[1];
            int s1 = c0 ? p[2] : p[3];
            int r0 = (c0 ? p[1] : p[0]) + __shfl_xor(s0, 1);
            int r1 = (c0 ? p[3] : p[2]) + __shfl_xor(s1, 1);
            int s2 = c1 ? r0 : r1;
            int fin = (c1 ? r1 : r0) + __shfl_xor(s2, 2);
            float y = sd * (float)fin + bd;
            if (tid < 512) Y[tid] = y + gid;
            else { Y[tid] = y; GN[tid - 512] = gid; }
        }
        __syncthreads();
        if (lead) {
            float r = fast_sigmoid(Y[tid]);
            float z = fast_sigmoid(Y[256 + tid]);
            float n = fast_tanh(GN[tid] + r * Y[512 + tid]);
            h = (1.0f - z) * n + z * h;
            *hop = h; hop += 256;
            ((signed char*)HQ)[tid] = (signed char)__float2int_rn(h * 127.0f);
        }
        __syncthreads();
    }
}

// ---------- Phase C1: logits = H(2048x256) @ out_W^T + b via bf16 MFMA ----------
// 256 threads = 4 waves; block tile 64(t) x 64(v); wave w owns m-tile w.
// Fragments loaded straight from global (coalesced 64B-line pattern), L2-resident.
__global__ __launch_bounds__(256) void k_logits(const unsigned short* __restrict__ hb,
                                                const unsigned short* __restrict__ wb,
                                                const float* __restrict__ out_b,
                                                float* __restrict__ out) {
    const int vb = blockIdx.x * 64;
    const int tb = blockIdx.y * 64;
    const int w = threadIdx.x >> 6;
    const int l = threadIdx.x & 63;
    const int m = l & 15;
    const int q = l >> 4;

    const unsigned short* aptr = hb + (size_t)(tb + w * 16 + m) * HDIM + q * 8;
    const unsigned short* bptr = wb + (size_t)(vb + m) * HDIM + q * 8;

    short8 af[8];
#pragma unroll
    for (int kt = 0; kt < 8; ++kt) af[kt] = *(const short8*)(aptr + kt * 32);

    f32x4 acc[4];
#pragma unroll
    for (int nt = 0; nt < 4; ++nt)
#pragma unroll
        for (int r = 0; r < 4; ++r) acc[nt][r] = 0.0f;

#pragma unroll
    for (int nt = 0; nt < 4; ++nt) {
        const unsigned short* bp = bptr + (size_t)nt * 16 * HDIM;
#pragma unroll
        for (int kt = 0; kt < 8; ++kt) {
            short8 bf = *(const short8*)(bp + kt * 32);
            acc[nt] = __builtin_amdgcn_mfma_f32_16x16x32_bf16(af[kt], bf, acc[nt], 0, 0, 0);
        }
    }
#pragma unroll
    for (int nt = 0; nt < 4; ++nt) {
        float bias = out_b[vb + nt * 16 + m];
#pragma unroll
        for (int r = 0; r < 4; ++r) {
            out[(size_t)(tb + w * 16 + q * 4 + r) * VOUT + vb + nt * 16 + m] =
                acc[nt][r] + bias;
        }
    }
}

// ---------- Phase C2: per-row logsumexp ----------
__global__ __launch_bounds__(256) void k_lse(const float* __restrict__ out,
                                             float* __restrict__ lse) {
    const int t = blockIdx.x;
    const int tid = threadIdx.x;
    const float* rowp = out + (size_t)t * VOUT;
    float m = -3.0e38f, l = 0.0f;
    for (int v = tid; v < VOUT; v += 256) {
        float x = rowp[v];
        float M = fmaxf(m, x);
        l = l * __expf(m - M) + __expf(x - M);
        m = M;
    }
#pragma unroll
    for (int off = 32; off; off >>= 1) {
        float m2 = __shfl_xor(m, off);
        float l2 = __shfl_xor(l, off);
        float M = fmaxf(m, m2);
        l = l * __expf(m - M) + l2 * __expf(m2 - M);
        m = M;
    }
    __shared__ float sm[4], sl[4];
    int lane = tid & 63, wv = tid >> 6;
    if (lane == 0) { sm[wv] = m; sl[wv] = l; }
    __syncthreads();
    if (tid == 0) {
        float M = fmaxf(fmaxf(sm[0], sm[1]), fmaxf(sm[2], sm[3]));
        float L = sl[0] * __expf(sm[0] - M) + sl[1] * __expf(sm[1] - M) +
                  sl[2] * __expf(sm[2] - M) + sl[3] * __expf(sm[3] - M);
        lse[t] = M + __logf(L);
    }
}

// ---------- Phase C3: out -= lse[t] ----------
__global__ __launch_bounds__(256) void k_sub(float* __restrict__ out,
                                             const float* __restrict__ lse) {
    const int t = blockIdx.y;
    const int v4 = blockIdx.x * 256 + threadIdx.x;
    if (v4 < VOUT / 4) {
        float s = lse[t];
        float4* p = (float4*)(out + (size_t)t * VOUT) + v4;
        float4 o = *p;
        o.x -= s; o.y -= s; o.z -= s; o.w -= s;
        *p = o;
    }
}

extern "C" void kernel_launch(void* const* d_in, const int* in_sizes, int n_in,
                              void* d_out, int out_size, void* d_ws, size_t ws_size,
                              hipStream_t stream) {
    (void)in_sizes; (void)n_in; (void)out_size; (void)ws_size;
    const int*   src      = (const int*)d_in[0];
    const int*   trg      = (const int*)d_in[1];
    const float* enc_emb  = (const float*)d_in[2];
    const float* enc_W_ih = (const float*)d_in[3];
    const float* enc_W_hh = (const float*)d_in[4];
    const float* enc_b_ih = (const float*)d_in[5];
    const float* enc_b_hh = (const float*)d_in[6];
    const float* dec_emb  = (const float*)d_in[7];
    const float* dec_W_ih = (const float*)d_in[8];
    const float* dec_W_hh = (const float*)d_in[9];
    const float* dec_b_ih = (const float*)d_in[10];
    const float* dec_b_hh = (const float*)d_in[11];
    const float* out_W    = (const float*)d_in[12];
    const float* out_b    = (const float*)d_in[13];
    float* out = (float*)d_out;

    char* ws = (char*)d_ws;
    float* gi_e  = (float*)ws; ws += (size_t)T_STEPS * 768 * 4;
    float* gi_d  = (float*)ws; ws += (size_t)T_STEPS * 768 * 4;
    float* h_all = (float*)ws; ws += (size_t)T_STEPS * HDIM * 4;
    float* lse   = (float*)ws; ws += (size_t)T_STEPS * 4;
    float* sc_e  = (float*)ws; ws += 768 * 4;
    float* sc_d  = (float*)ws; ws += 768 * 4;
    int*   wq_e  = (int*)ws;   ws += 768 * 64 * 4;
    int*   wq_d  = (int*)ws;   ws += 768 * 64 * 4;
    unsigned short* h_bf = (unsigned short*)ws; ws += (size_t)T_STEPS * HDIM * 2;
    unsigned short* w_bf = (unsigned short*)ws; ws += (size_t)VOUT * HDIM * 2;

    k_quant<<<768, 64, 0, stream>>>(enc_W_hh, wq_e, sc_e);
    k_quant<<<768, 64, 0, stream>>>(dec_W_hh, wq_d, sc_d);
    k_cvt<<<(VOUT * HDIM / 4 + 255) / 256, 256, 0, stream>>>(out_W, w_bf, VOUT * HDIM / 4);
    k_gi<<<T_STEPS, 256, 0, stream>>>(src, enc_emb, enc_W_ih, enc_b_ih, gi_e, 0);
    k_gi<<<T_STEPS, 256, 0, stream>>>(trg, dec_emb, dec_W_ih, dec_b_ih, gi_d, 1);
    k_gru<<<1, 768, 0, stream>>>(wq_e, sc_e, enc_b_hh, gi_e,
                                 wq_d, sc_d, dec_b_hh, gi_d, h_all);
    k_cvt<<<(T_STEPS * HDIM / 4 + 255) / 256, 256, 0, stream>>>(h_all, h_bf, T_STEPS * HDIM / 4);
    k_logits<<<dim3(VOUT / 64, T_STEPS / 64), 256, 0, stream>>>(h_bf, w_bf, out_b, out);
    k_lse<<<T_STEPS, 256, 0, stream>>>(out, lse);
    k_sub<<<dim3(32, T_STEPS), 256, 0, stream>>>(out, lse);
}